// Round 3
// baseline (3861.176 us; speedup 1.0000x reference)
//
#include <hip/hip_runtime.h>
#include <math.h>

#define B 64
#define T 20
#define C 512
#define HW 196
#define V 10000
#define E 256
#define U 512
#define G4U 2048
#define ODIM 1280
#define KTOT 1280

typedef short bf8_t __attribute__((ext_vector_type(8)));
typedef float f4_t  __attribute__((ext_vector_type(4)));

__device__ __forceinline__ unsigned short f2bf(float f) {
    unsigned int u = __float_as_uint(f);
    return (unsigned short)((u + 0x7fffu + ((u >> 16) & 1u)) >> 16);
}
__device__ __forceinline__ float bflo(unsigned int kv) { return __uint_as_float(kv << 16); }
__device__ __forceinline__ float bfhi(unsigned int kv) { return __uint_as_float(kv & 0xffff0000u); }

// ---------- feats_mean ----------
__global__ void k_mean(const float* __restrict__ img, float* __restrict__ fm) {
    int wave = threadIdx.x >> 6;
    int lane = threadIdx.x & 63;
    int row = blockIdx.x * 4 + wave;
    const float* p = img + (size_t)row * HW;
    float s = p[lane] + p[lane + 64] + p[lane + 128];
    if (lane < 4) s += p[lane + 192];
    for (int off = 32; off > 0; off >>= 1) s += __shfl_down(s, off, 64);
    if (lane == 0) fm[row] = s * (1.0f / HW);
}

// ---------- hid0 -> xbuf hid slot, cell0 ----------
__global__ void k_init(const float* __restrict__ fm,
                       const float* __restrict__ W_h0, const float* __restrict__ b_h0,
                       const float* __restrict__ W_c0, const float* __restrict__ b_c0,
                       float* __restrict__ xbuf, float* __restrict__ cell) {
    int wv = blockIdx.x * 4 + (threadIdx.x >> 6);
    int lane = threadIdx.x & 63;
    int which = wv >> 15;
    int r = wv & 32767;
    int b = r >> 9, u = r & 511;
    const float* W = which ? W_c0 : W_h0;
    const float* bias = which ? b_c0 : b_h0;
    const float* f = fm + b * C;
    const float* w = W + (size_t)u * C;
    float s = 0.f;
    #pragma unroll
    for (int c = 0; c < C; c += 64) s += f[c + lane] * w[c + lane];
    for (int off = 32; off > 0; off >>= 1) s += __shfl_down(s, off, 64);
    if (lane == 0) {
        float v = s + bias[u];
        if (which) cell[r] = v;
        else       xbuf[(size_t)b * KTOT + 768 + u] = v;
    }
}

// ---------- keys -> keys2[b][k][u] bf16 (k-major) ----------
__global__ void k_keys(const float* __restrict__ img, const float* __restrict__ W_key,
                       const float* __restrict__ b_key, unsigned short* __restrict__ keys2) {
    __shared__ float Ws[8 * C];
    int b = blockIdx.x / (U / 8);
    int u0 = (blockIdx.x % (U / 8)) * 8;
    for (int i = threadIdx.x; i < 8 * C; i += 512)
        Ws[i] = W_key[(size_t)u0 * C + i];
    __syncthreads();
    int wave = threadIdx.x >> 6, lane = threadIdx.x & 63;
    int u = u0 + wave;
    const float4* imgb = (const float4*)(img + (size_t)b * C * HW);
    if (lane < 49) {
        float4 acc = {0.f, 0.f, 0.f, 0.f};
        for (int c = 0; c < C; c++) {
            float w = Ws[wave * C + c];
            float4 v = imgb[c * 49 + lane];
            acc.x += w * v.x; acc.y += w * v.y; acc.z += w * v.z; acc.w += w * v.w;
        }
        float bk = b_key[u];
        acc.x += bk; acc.y += bk; acc.z += bk; acc.w += bk;
        int k0 = lane * 4;
        unsigned short* kp = keys2 + ((size_t)b * HW + k0) * U + u;
        kp[0 * U] = f2bf(acc.x);
        kp[1 * U] = f2bf(acc.y);
        kp[2 * U] = f2bf(acc.z);
        kp[3 * U] = f2bf(acc.w);
    }
}

// ---------- WT[k][j] = concat(W_ih, W_hh) transposed ----------
__global__ void k_wt(const float* __restrict__ W_ih, const float* __restrict__ W_hh,
                     float* __restrict__ WT) {
    __shared__ float tile[64][65];
    int j0 = blockIdx.x * 64;          // 32 blocks
    int k0 = blockIdx.y * 64;          // 20 blocks
    int c = threadIdx.x & 63;
    int r0 = threadIdx.x >> 6;
    #pragma unroll
    for (int i = 0; i < 16; i++) {
        int r = r0 * 16 + i;           // j-local
        int j = j0 + r, k = k0 + c;
        float v;
        if (k0 < 768) v = W_ih[(size_t)j * 768 + k];
        else          v = W_hh[(size_t)j * 512 + (k - 768)];
        tile[r][c] = v;
    }
    __syncthreads();
    #pragma unroll
    for (int i = 0; i < 16; i++) {
        int r = r0 * 16 + i;           // k-local
        WT[(size_t)(k0 + r) * G4U + j0 + c] = tile[c][r];
    }
}

// ---------- embedding gather + renorm -> outs emb slot ----------
__global__ void k_emb(const int* __restrict__ ix, const float* __restrict__ emb,
                      float* __restrict__ outs) {
    int bt = blockIdx.x;
    int e = threadIdx.x;
    int row = ix[bt];
    float v = emb[(size_t)row * E + e];
    __shared__ float red[4];
    float sq = v * v;
    for (int off = 32; off > 0; off >>= 1) sq += __shfl_down(sq, off, 64);
    int wave = e >> 6, lane = e & 63;
    if (lane == 0) red[wave] = sq;
    __syncthreads();
    float norm = sqrtf(red[0] + red[1] + red[2] + red[3]);
    float scale = fminf(1.0f, 5.0f / fmaxf(norm, 1e-12f));
    outs[(size_t)bt * ODIM + (U + C) + e] = v * scale;
}

// ---------- A-kernel: pointwise (t>0) + attention (t<20); one block per b ----------
__global__ __launch_bounds__(256) void k_step(
    float* __restrict__ outs, float* __restrict__ xbuf, float* __restrict__ cell,
    const float* __restrict__ gates_buf, const unsigned short* __restrict__ keys2,
    const float* __restrict__ img,
    const float* __restrict__ b_ih, const float* __restrict__ b_hh,
    float* __restrict__ attn, int t) {
    int b = blockIdx.x;
    int tid = threadIdx.x;
    int wave = tid >> 6, lane = tid & 63;
    __shared__ float hidS[U];
    __shared__ float sS[256];
    __shared__ float wS[256];
    __shared__ float aS[C];
    __shared__ float red[4];

    // ---- pointwise LSTM (produce hid_t from gates_{t-1}) ----
    if (t > 0) {
        #pragma unroll
        for (int p = 0; p < 2; p++) {
            int u = tid + p * 256;
            float g[4];
            #pragma unroll
            for (int q = 0; q < 4; q++) {
                int j = q * 512 + u;
                g[q] = gates_buf[(size_t)b * G4U + j] + b_ih[j] + b_hh[j];
            }
            float si = 1.f / (1.f + expf(-g[0]));
            float sf = 1.f / (1.f + expf(-g[1]));
            float tg = tanhf(g[2]);
            float so = 1.f / (1.f + expf(-g[3]));
            int ci = b * U + u;
            float cn = sf * cell[ci] + si * tg;
            float hn = so * tanhf(cn);
            cell[ci] = cn;
            hidS[u] = hn;
            outs[((size_t)b * T + (t - 1)) * ODIM + u] = hn;
            xbuf[(size_t)b * KTOT + 768 + u] = hn;
        }
    } else {
        #pragma unroll
        for (int p = 0; p < 2; p++) {
            int u = tid + p * 256;
            hidS[u] = xbuf[(size_t)b * KTOT + 768 + u];
        }
    }
    if (t >= T) return;
    __syncthreads();

    // ---- scores: s[k] = (1/sqrt(U)) * sum_u hid[u]*keys2[b][k][u] ----
    {
        const unsigned int* kbase = (const unsigned int*)(keys2 + (size_t)b * HW * U);
        for (int i = 0; i < 49; i++) {
            int k = wave * 49 + i;
            const unsigned int* kr = kbase + (size_t)k * (U / 2);
            float acc = 0.f;
            #pragma unroll
            for (int i2 = 0; i2 < 4; i2++) {
                unsigned int kv = kr[i2 * 64 + lane];
                float2 hp = *(const float2*)&hidS[2 * (i2 * 64 + lane)];
                acc += bflo(kv) * hp.x + bfhi(kv) * hp.y;
            }
            for (int off = 32; off > 0; off >>= 1) acc += __shfl_down(acc, off, 64);
            if (lane == 0) sS[k] = acc * 0.044194173824159216f;
        }
    }
    __syncthreads();

    // ---- softmax over 196 ----
    {
        float v = (tid < HW) ? sS[tid] : -1e30f;
        float m = v;
        for (int off = 32; off > 0; off >>= 1) m = fmaxf(m, __shfl_down(m, off, 64));
        if (lane == 0) red[wave] = m;
        __syncthreads();
        m = fmaxf(fmaxf(red[0], red[1]), fmaxf(red[2], red[3]));
        float ex = (tid < HW) ? expf(v - m) : 0.f;
        float ssum = ex;
        for (int off = 32; off > 0; off >>= 1) ssum += __shfl_down(ssum, off, 64);
        __syncthreads();
        if (lane == 0) red[wave] = ssum;
        __syncthreads();
        ssum = red[0] + red[1] + red[2] + red[3];
        float w = ex / ssum;
        wS[tid] = w;
        if (tid < HW) attn[((size_t)b * T + t) * HW + tid] = w;
    }
    __syncthreads();

    // ---- context: a[c] = sum_k w[k]*img[b][c][k] ----
    {
        const float* imgb = img + (size_t)b * C * HW;
        for (int i = 0; i < 128; i++) {
            int c = wave * 128 + i;
            const float* r = imgb + (size_t)c * HW;
            float acc = r[lane] * wS[lane] + r[lane + 64] * wS[lane + 64]
                      + r[lane + 128] * wS[lane + 128];
            if (lane < 4) acc += r[lane + 192] * wS[lane + 192];
            for (int off = 32; off > 0; off >>= 1) acc += __shfl_down(acc, off, 64);
            if (lane == 0) aS[c] = acc;
        }
    }
    __syncthreads();

    // ---- writes: a -> xbuf + outs; emb_t -> xbuf ----
    #pragma unroll
    for (int p = 0; p < 2; p++) {
        int c = tid + p * 256;
        float a = aS[c];
        xbuf[(size_t)b * KTOT + 256 + c] = a;
        outs[((size_t)b * T + t) * ODIM + U + c] = a;
    }
    xbuf[(size_t)b * KTOT + tid] = outs[((size_t)b * T + t) * ODIM + 1024 + tid];
}

// ---------- G-kernel: gates_buf[b][j] = sum_k x[b][k]*WT[k][j] ----------
// grid: 256 blocks = (jw 0..31) x (bg 0..7); wave w handles k-slice [w*320,(w+1)*320)
__global__ __launch_bounds__(256) void k_gates3(
    const float* __restrict__ xbuf, const float* __restrict__ WT,
    float* __restrict__ gates_buf) {
    __shared__ float red[4][8][64];
    int jw = blockIdx.x & 31;
    int bg = blockIdx.x >> 5;
    int lane = threadIdx.x & 63;
    int w = __builtin_amdgcn_readfirstlane(threadIdx.x >> 6);
    int j = jw * 64 + lane;
    int bbase = bg * 8;
    int k0 = w * 320;
    const float* wtp = WT + (size_t)k0 * G4U + j;
    const float* xb = xbuf + (size_t)bbase * KTOT + k0;
    float acc[8] = {};
    for (int kk = 0; kk < 320; kk += 4) {
        float wt0 = wtp[(size_t)(kk + 0) * G4U];
        float wt1 = wtp[(size_t)(kk + 1) * G4U];
        float wt2 = wtp[(size_t)(kk + 2) * G4U];
        float wt3 = wtp[(size_t)(kk + 3) * G4U];
        #pragma unroll
        for (int i = 0; i < 8; i++) {
            const float* xr = xb + (size_t)i * KTOT + kk;
            acc[i] += wt0 * xr[0] + wt1 * xr[1] + wt2 * xr[2] + wt3 * xr[3];
        }
    }
    #pragma unroll
    for (int i = 0; i < 8; i++) red[w][i][lane] = acc[i];
    __syncthreads();
    int iw = threadIdx.x >> 6;
    #pragma unroll
    for (int p = 0; p < 2; p++) {
        int i = iw + p * 4;
        float v = red[0][i][lane] + red[1][i][lane] + red[2][i][lane] + red[3][i][lane];
        gates_buf[(size_t)(bbase + i) * G4U + jw * 64 + lane] = v;
    }
}

// ---------- logits: bf16 MFMA, 256x256 tile ----------
__global__ __launch_bounds__(256) void k_logits3(
    const float* __restrict__ A, const float* __restrict__ Wo,
    const float* __restrict__ bo, float* __restrict__ Cout) {
    __shared__ unsigned short As[256][40];
    __shared__ unsigned short Bs[256][40];
    int n0 = blockIdx.x * 256;
    int m0 = blockIdx.y * 256;
    int tid = threadIdx.x;
    int lane = tid & 63;
    int wv = tid >> 6;
    int mbw = (wv >> 1) * 128;   // wave m-base within tile
    int nbw = (wv & 1) * 128;    // wave n-base within tile
    int rg = tid >> 3;           // 0..31 row group for staging
    int kq = tid & 7;            // float4 index in k-chunk
    int quad8 = (lane >> 4) * 8;
    int m16 = lane & 15;

    f4_t acc[8][8];
    #pragma unroll
    for (int i = 0; i < 8; i++)
        #pragma unroll
        for (int jj = 0; jj < 8; jj++)
            acc[i][jj] = (f4_t){0.f, 0.f, 0.f, 0.f};

    for (int k0 = 0; k0 < KTOT; k0 += 32) {
        __syncthreads();
        #pragma unroll
        for (int rr = 0; rr < 8; rr++) {
            int row = rg + rr * 32;
            float4 av = *(const float4*)&A[(size_t)(m0 + row) * KTOT + k0 + kq * 4];
            unsigned int p0 = ((unsigned int)f2bf(av.y) << 16) | f2bf(av.x);
            unsigned int p1 = ((unsigned int)f2bf(av.w) << 16) | f2bf(av.z);
            *(uint2*)&As[row][kq * 4] = (uint2){p0, p1};
            int n = n0 + row;
            float4 bv = {0.f, 0.f, 0.f, 0.f};
            if (n < V) bv = *(const float4*)&Wo[(size_t)n * KTOT + k0 + kq * 4];
            unsigned int q0 = ((unsigned int)f2bf(bv.y) << 16) | f2bf(bv.x);
            unsigned int q1 = ((unsigned int)f2bf(bv.w) << 16) | f2bf(bv.z);
            *(uint2*)&Bs[row][kq * 4] = (uint2){q0, q1};
        }
        __syncthreads();
        bf8_t af[8], bf[8];
        #pragma unroll
        for (int i = 0; i < 8; i++)
            af[i] = *(const bf8_t*)&As[mbw + i * 16 + m16][quad8];
        #pragma unroll
        for (int jj = 0; jj < 8; jj++)
            bf[jj] = *(const bf8_t*)&Bs[nbw + jj * 16 + m16][quad8];
        #pragma unroll
        for (int i = 0; i < 8; i++)
            #pragma unroll
            for (int jj = 0; jj < 8; jj++)
                acc[i][jj] = __builtin_amdgcn_mfma_f32_16x16x32_bf16(af[i], bf[jj], acc[i][jj], 0, 0, 0);
    }

    int rbase = (lane >> 4) * 4;
    #pragma unroll
    for (int jj = 0; jj < 8; jj++) {
        int n = n0 + nbw + jj * 16 + m16;
        if (n >= V) continue;
        float bias = bo[n];
        #pragma unroll
        for (int i = 0; i < 8; i++) {
            int mb = m0 + mbw + i * 16 + rbase;
            #pragma unroll
            for (int r = 0; r < 4; r++)
                Cout[(size_t)(mb + r) * V + n] = acc[i][jj][r] + bias;
        }
    }
}

extern "C" void kernel_launch(void* const* d_in, const int* in_sizes, int n_in,
                              void* d_out, int out_size, void* d_ws, size_t ws_size,
                              hipStream_t stream) {
    const float* img   = (const float*)d_in[0];
    const int*   capix = (const int*)d_in[1];
    const float* W_h0  = (const float*)d_in[2];
    const float* b_h0  = (const float*)d_in[3];
    const float* W_c0  = (const float*)d_in[4];
    const float* b_c0  = (const float*)d_in[5];
    const float* emb   = (const float*)d_in[6];
    const float* W_key = (const float*)d_in[7];
    const float* b_key = (const float*)d_in[8];
    const float* W_ih  = (const float*)d_in[9];
    const float* b_ih  = (const float*)d_in[10];
    const float* W_hh  = (const float*)d_in[11];
    const float* b_hh  = (const float*)d_in[12];
    const float* W_out = (const float*)d_in[13];
    const float* b_out = (const float*)d_in[14];

    float* ws = (float*)d_ws;
    float* gates_buf = ws;                       // 131072 (fm overlaid)
    float* fm        = ws;                       // 32768, dead before G_0
    float* xbuf      = gates_buf + 131072;       // 64*1280 = 81920
    float* cell      = xbuf + 81920;             // 32768
    float* outs      = cell + 32768;             // 1638400
    float* WT        = outs + 1638400;           // 1280*2048 = 2621440
    unsigned short* keys2 = (unsigned short*)(WT + 2621440);  // B*HW*U bf16 = 12.8 MB

    float* logits = (float*)d_out;
    float* attn   = logits + (size_t)B * T * V;

    k_mean<<<(B * C) / 4, 256, 0, stream>>>(img, fm);
    k_init<<<(2 * B * U) / 4, 256, 0, stream>>>(fm, W_h0, b_h0, W_c0, b_c0, xbuf, cell);
    k_keys<<<B * (U / 8), 512, 0, stream>>>(img, W_key, b_key, keys2);
    k_wt<<<dim3(32, 20), 256, 0, stream>>>(W_ih, W_hh, WT);
    k_emb<<<B * T, 256, 0, stream>>>(capix, emb, outs);

    for (int t = 0; t < T; t++) {
        k_step<<<B, 256, 0, stream>>>(outs, xbuf, cell, gates_buf, keys2, img,
                                      b_ih, b_hh, attn, t);
        k_gates3<<<256, 256, 0, stream>>>(xbuf, WT, gates_buf);
    }
    // final pointwise: hid_20 -> outs[:,19,:]
    k_step<<<B, 256, 0, stream>>>(outs, xbuf, cell, gates_buf, keys2, img,
                                  b_ih, b_hh, attn, T);

    k_logits3<<<dim3((V + 255) / 256, (B * T) / 256), 256, 0, stream>>>(outs, W_out, b_out, logits);
}

// Round 4
// 2592.857 us; speedup vs baseline: 1.4892x; 1.4892x over previous
//
#include <hip/hip_runtime.h>
#include <math.h>

#define B 64
#define T 20
#define C 512
#define HW 196
#define V 10000
#define E 256
#define U 512
#define G4U 2048
#define ODIM 1280
#define KTOT 1280

typedef short bf8_t __attribute__((ext_vector_type(8)));
typedef float f4_t  __attribute__((ext_vector_type(4)));

__device__ __forceinline__ unsigned short f2bf(float f) {
    unsigned int u = __float_as_uint(f);
    return (unsigned short)((u + 0x7fffu + ((u >> 16) & 1u)) >> 16);
}
__device__ __forceinline__ float bf2f(unsigned short s) {
    return __uint_as_float((unsigned int)s << 16);
}
__device__ __forceinline__ float bflo(unsigned int kv) { return __uint_as_float(kv << 16); }
__device__ __forceinline__ float bfhi(unsigned int kv) { return __uint_as_float(kv & 0xffff0000u); }

// ---------- feats_mean ----------
__global__ void k_mean(const float* __restrict__ img, float* __restrict__ fm) {
    int wave = threadIdx.x >> 6;
    int lane = threadIdx.x & 63;
    int row = blockIdx.x * 4 + wave;
    const float* p = img + (size_t)row * HW;
    float s = p[lane] + p[lane + 64] + p[lane + 128];
    if (lane < 4) s += p[lane + 192];
    for (int off = 32; off > 0; off >>= 1) s += __shfl_down(s, off, 64);
    if (lane == 0) fm[row] = s * (1.0f / HW);
}

// ---------- hid0 -> xbuf hid slot, cell0 ----------
__global__ void k_init(const float* __restrict__ fm,
                       const float* __restrict__ W_h0, const float* __restrict__ b_h0,
                       const float* __restrict__ W_c0, const float* __restrict__ b_c0,
                       float* __restrict__ xbuf, float* __restrict__ cell) {
    int wv = blockIdx.x * 4 + (threadIdx.x >> 6);
    int lane = threadIdx.x & 63;
    int which = wv >> 15;
    int r = wv & 32767;
    int b = r >> 9, u = r & 511;
    const float* W = which ? W_c0 : W_h0;
    const float* bias = which ? b_c0 : b_h0;
    const float* f = fm + b * C;
    const float* w = W + (size_t)u * C;
    float s = 0.f;
    #pragma unroll
    for (int c = 0; c < C; c += 64) s += f[c + lane] * w[c + lane];
    for (int off = 32; off > 0; off >>= 1) s += __shfl_down(s, off, 64);
    if (lane == 0) {
        float v = s + bias[u];
        if (which) cell[r] = v;
        else       xbuf[(size_t)b * KTOT + 768 + u] = v;
    }
}

// ---------- W_keyT[c][u] ----------
__global__ void k_wkt(const float* __restrict__ Wk, float* __restrict__ WkT) {
    __shared__ float tile[64][65];
    int u0 = blockIdx.x * 64, c0 = blockIdx.y * 64;
    int x = threadIdx.x & 63, y0 = threadIdx.x >> 6;
    #pragma unroll
    for (int i = 0; i < 16; i++) {
        int r = y0 * 16 + i;
        tile[r][x] = Wk[(size_t)(u0 + r) * C + c0 + x];
    }
    __syncthreads();
    #pragma unroll
    for (int i = 0; i < 16; i++) {
        int r = y0 * 16 + i;
        WkT[(size_t)(c0 + r) * U + u0 + x] = tile[x][r];
    }
}

// ---------- keys2[b][k][u] bf16; 8-u register blocking, SGPR weight broadcast ----------
__global__ __launch_bounds__(256) void k_keys(const float* __restrict__ img,
        const float* __restrict__ WkT, const float* __restrict__ b_key,
        unsigned short* __restrict__ keys2) {
    __shared__ unsigned short st[32][200];
    int b = blockIdx.x >> 4;
    int u0 = (blockIdx.x & 15) * 32;
    int wave = __builtin_amdgcn_readfirstlane(threadIdx.x >> 6);
    int lane = threadIdx.x & 63;
    int lk = lane < 49 ? lane : 48;
    const f4_t* imgb = (const f4_t*)(img + (size_t)b * C * HW);
    f4_t acc[8];
    #pragma unroll
    for (int j = 0; j < 8; j++) acc[j] = (f4_t){0.f, 0.f, 0.f, 0.f};
    const float* wp = WkT + u0 + wave * 8;
    for (int c = 0; c < C; c++) {
        f4_t v = imgb[c * 49 + lk];
        const float* w = wp + (size_t)c * U;
        #pragma unroll
        for (int j = 0; j < 8; j++) acc[j] += v * w[j];
    }
    if (lane < 49) {
        #pragma unroll
        for (int j = 0; j < 8; j++) {
            float bk = b_key[u0 + wave * 8 + j];
            int ul = wave * 8 + j;
            int k = lane * 4;
            st[ul][k + 0] = f2bf(acc[j].x + bk);
            st[ul][k + 1] = f2bf(acc[j].y + bk);
            st[ul][k + 2] = f2bf(acc[j].z + bk);
            st[ul][k + 3] = f2bf(acc[j].w + bk);
        }
    }
    __syncthreads();
    int ui = threadIdx.x & 15;
    int kr = threadIdx.x >> 4;
    #pragma unroll
    for (int pass = 0; pass < 13; pass++) {
        int k = pass * 16 + kr;
        if (k < HW) {
            unsigned int lo = st[ui * 2][k];
            unsigned int hi = st[ui * 2 + 1][k];
            *(unsigned int*)&keys2[((size_t)b * HW + k) * U + u0 + ui * 2] = (hi << 16) | lo;
        }
    }
}

// ---------- WT[k][j] = concat(W_ih, W_hh) transposed ----------
__global__ void k_wt(const float* __restrict__ W_ih, const float* __restrict__ W_hh,
                     float* __restrict__ WT) {
    __shared__ float tile[64][65];
    int j0 = blockIdx.x * 64;
    int k0 = blockIdx.y * 64;
    int c = threadIdx.x & 63;
    int r0 = threadIdx.x >> 6;
    #pragma unroll
    for (int i = 0; i < 16; i++) {
        int r = r0 * 16 + i;
        int j = j0 + r, k = k0 + c;
        float v;
        if (k0 < 768) v = W_ih[(size_t)j * 768 + k];
        else          v = W_hh[(size_t)j * 512 + (k - 768)];
        tile[r][c] = v;
    }
    __syncthreads();
    #pragma unroll
    for (int i = 0; i < 16; i++) {
        int r = r0 * 16 + i;
        WT[(size_t)(k0 + r) * G4U + j0 + c] = tile[c][r];
    }
}

// ---------- embedding gather + renorm -> outs (bf16) emb slot ----------
__global__ void k_emb(const int* __restrict__ ix, const float* __restrict__ emb,
                      unsigned short* __restrict__ outs) {
    int bt = blockIdx.x;
    int e = threadIdx.x;
    int row = ix[bt];
    float v = emb[(size_t)row * E + e];
    __shared__ float red[4];
    float sq = v * v;
    for (int off = 32; off > 0; off >>= 1) sq += __shfl_down(sq, off, 64);
    int wave = e >> 6, lane = e & 63;
    if (lane == 0) red[wave] = sq;
    __syncthreads();
    float norm = sqrtf(red[0] + red[1] + red[2] + red[3]);
    float scale = fminf(1.0f, 5.0f / fmaxf(norm, 1e-12f));
    outs[(size_t)bt * ODIM + (U + C) + e] = f2bf(v * scale);
}

// ---------- A-kernel: pointwise + attention; one block per b ----------
__global__ __launch_bounds__(256) void k_step(
    unsigned short* __restrict__ outs, float* __restrict__ xbuf, float* __restrict__ cell,
    const float* __restrict__ gates_buf, const unsigned short* __restrict__ keys2,
    const float* __restrict__ img,
    const float* __restrict__ b_ih, const float* __restrict__ b_hh,
    float* __restrict__ attn, int t) {
    int b = blockIdx.x;
    int tid = threadIdx.x;
    int wave = tid >> 6, lane = tid & 63;
    int wave_u = __builtin_amdgcn_readfirstlane(wave);
    __shared__ float hidS[U];
    __shared__ float sS[200];
    __shared__ float wS[256];
    __shared__ float red[4];

    if (t > 0) {
        #pragma unroll
        for (int p = 0; p < 2; p++) {
            int u = tid + p * 256;
            float g[4];
            #pragma unroll
            for (int q = 0; q < 4; q++) {
                int j = q * 512 + u;
                g[q] = gates_buf[(size_t)b * G4U + j] + b_ih[j] + b_hh[j];
            }
            float si = 1.f / (1.f + expf(-g[0]));
            float sf = 1.f / (1.f + expf(-g[1]));
            float tg = tanhf(g[2]);
            float so = 1.f / (1.f + expf(-g[3]));
            int ci = b * U + u;
            float cn = sf * cell[ci] + si * tg;
            float hn = so * tanhf(cn);
            cell[ci] = cn;
            hidS[u] = hn;
            outs[((size_t)b * T + (t - 1)) * ODIM + u] = f2bf(hn);
            xbuf[(size_t)b * KTOT + 768 + u] = hn;
        }
    } else {
        #pragma unroll
        for (int p = 0; p < 2; p++) {
            int u = tid + p * 256;
            hidS[u] = xbuf[(size_t)b * KTOT + 768 + u];
        }
    }
    if (t >= T) return;
    __syncthreads();

    // scores: s[k] = (1/sqrt(U)) * sum_u hid[u]*keys2[b][k][u]
    {
        const unsigned int* kb = (const unsigned int*)(keys2 + (size_t)b * HW * U);
        for (int i = 0; i < 49; i++) {
            int k = wave_u * 49 + i;
            const unsigned int* kr = kb + (size_t)k * (U / 2);
            float acc = 0.f;
            #pragma unroll
            for (int h = 0; h < 2; h++) {
                uint2 kv = *(const uint2*)&kr[(h * 64 + lane) * 2];
                float4 hv = *(const float4*)&hidS[(h * 64 + lane) * 4];
                acc += bflo(kv.x) * hv.x + bfhi(kv.x) * hv.y
                     + bflo(kv.y) * hv.z + bfhi(kv.y) * hv.w;
            }
            for (int off = 32; off > 0; off >>= 1) acc += __shfl_down(acc, off, 64);
            if (lane == 0) sS[k] = acc * 0.044194173824159216f;
        }
    }
    __syncthreads();

    // softmax over 196
    {
        float v = (tid < HW) ? sS[tid] : -1e30f;
        float m = v;
        for (int off = 32; off > 0; off >>= 1) m = fmaxf(m, __shfl_down(m, off, 64));
        if (lane == 0) red[wave] = m;
        __syncthreads();
        m = fmaxf(fmaxf(red[0], red[1]), fmaxf(red[2], red[3]));
        float ex = (tid < HW) ? expf(v - m) : 0.f;
        float ssum = ex;
        for (int off = 32; off > 0; off >>= 1) ssum += __shfl_down(ssum, off, 64);
        __syncthreads();
        if (lane == 0) red[wave] = ssum;
        __syncthreads();
        ssum = red[0] + red[1] + red[2] + red[3];
        float w = ex / ssum;
        wS[tid] = w;
        if (tid < HW) attn[((size_t)b * T + t) * HW + tid] = w;
    }
    __syncthreads();

    // context: thread-per-c full dot over k
    {
        const float4* imgb = (const float4*)(img + (size_t)b * C * HW);
        #pragma unroll
        for (int p = 0; p < 2; p++) {
            int c = tid + p * 256;
            const float4* r = imgb + c * 49;
            float acc = 0.f;
            for (int k4 = 0; k4 < 49; k4++) {
                float4 v = r[k4];
                acc += wS[4 * k4] * v.x + wS[4 * k4 + 1] * v.y
                     + wS[4 * k4 + 2] * v.z + wS[4 * k4 + 3] * v.w;
            }
            xbuf[(size_t)b * KTOT + 256 + c] = acc;
            outs[((size_t)b * T + t) * ODIM + U + c] = f2bf(acc);
        }
    }
    // emb -> xbuf
    xbuf[(size_t)b * KTOT + tid] = bf2f(outs[((size_t)b * T + t) * ODIM + 1024 + tid]);
}

// ---------- gates: LDS-staged x broadcast, coalesced WT ----------
__global__ __launch_bounds__(256) void k_gates4(const float* __restrict__ xbuf,
        const float* __restrict__ WT, float* __restrict__ gates_buf) {
    __shared__ float xS[8][KTOT];
    __shared__ float red[4][8][64];
    int jw = blockIdx.x & 31;
    int bg = blockIdx.x >> 5;
    int bbase = bg * 8;
    int tid = threadIdx.x;
    #pragma unroll
    for (int i = 0; i < 8; i++)
        for (int k = tid; k < KTOT; k += 256)
            xS[i][k] = xbuf[(size_t)(bbase + i) * KTOT + k];
    __syncthreads();
    int w = __builtin_amdgcn_readfirstlane(tid >> 6);
    int lane = tid & 63;
    int k0 = w * 320;
    const float* wtp = WT + (size_t)k0 * G4U + jw * 64 + lane;
    float acc[8] = {};
    #pragma unroll 2
    for (int kk = 0; kk < 320; kk += 2) {
        float wt0 = wtp[(size_t)kk * G4U];
        float wt1 = wtp[(size_t)(kk + 1) * G4U];
        #pragma unroll
        for (int i = 0; i < 8; i++) {
            float2 x2 = *(const float2*)&xS[i][k0 + kk];
            acc[i] += wt0 * x2.x + wt1 * x2.y;
        }
    }
    #pragma unroll
    for (int i = 0; i < 8; i++) red[w][i][lane] = acc[i];
    __syncthreads();
    int iw = tid >> 6;
    #pragma unroll
    for (int p = 0; p < 2; p++) {
        int i = iw + p * 4;
        float v = red[0][i][lane] + red[1][i][lane] + red[2][i][lane] + red[3][i][lane];
        gates_buf[(size_t)(bbase + i) * G4U + jw * 64 + lane] = v;
    }
}

// ---------- logits: bf16 MFMA, 256x256 tile; A already bf16 ----------
__global__ __launch_bounds__(256) void k_logits3(
    const unsigned short* __restrict__ A, const float* __restrict__ Wo,
    const float* __restrict__ bo, float* __restrict__ Cout) {
    __shared__ unsigned short As[256][40];
    __shared__ unsigned short Bs[256][40];
    int n0 = blockIdx.x * 256;
    int m0 = blockIdx.y * 256;
    int tid = threadIdx.x;
    int lane = tid & 63;
    int wv = tid >> 6;
    int mbw = (wv >> 1) * 128;
    int nbw = (wv & 1) * 128;
    int rg = tid >> 3;
    int kq = tid & 7;
    int quad8 = (lane >> 4) * 8;
    int m16 = lane & 15;

    f4_t acc[8][8];
    #pragma unroll
    for (int i = 0; i < 8; i++)
        #pragma unroll
        for (int jj = 0; jj < 8; jj++)
            acc[i][jj] = (f4_t){0.f, 0.f, 0.f, 0.f};

    for (int k0 = 0; k0 < KTOT; k0 += 32) {
        __syncthreads();
        #pragma unroll
        for (int rr = 0; rr < 8; rr++) {
            int row = rg + rr * 32;
            uint2 av = *(const uint2*)&A[(size_t)(m0 + row) * KTOT + k0 + kq * 4];
            *(uint2*)&As[row][kq * 4] = av;
            int n = n0 + row;
            float4 bv = {0.f, 0.f, 0.f, 0.f};
            if (n < V) bv = *(const float4*)&Wo[(size_t)n * KTOT + k0 + kq * 4];
            unsigned int q0 = ((unsigned int)f2bf(bv.y) << 16) | f2bf(bv.x);
            unsigned int q1 = ((unsigned int)f2bf(bv.w) << 16) | f2bf(bv.z);
            *(uint2*)&Bs[row][kq * 4] = (uint2){q0, q1};
        }
        __syncthreads();
        bf8_t af[8], bf[8];
        #pragma unroll
        for (int i = 0; i < 8; i++)
            af[i] = *(const bf8_t*)&As[mbw + i * 16 + m16][quad8];
        #pragma unroll
        for (int jj = 0; jj < 8; jj++)
            bf[jj] = *(const bf8_t*)&Bs[nbw + jj * 16 + m16][quad8];
        #pragma unroll
        for (int i = 0; i < 8; i++)
            #pragma unroll
            for (int jj = 0; jj < 8; jj++)
                acc[i][jj] = __builtin_amdgcn_mfma_f32_16x16x32_bf16(af[i], bf[jj], acc[i][jj], 0, 0, 0);
    }

    int rbase = (lane >> 4) * 4;
    #pragma unroll
    for (int jj = 0; jj < 8; jj++) {
        int n = n0 + nbw + jj * 16 + m16;
        if (n >= V) continue;
        float bias = bo[n];
        #pragma unroll
        for (int i = 0; i < 8; i++) {
            int mb = m0 + mbw + i * 16 + rbase;
            #pragma unroll
            for (int r = 0; r < 4; r++)
                Cout[(size_t)(mb + r) * V + n] = acc[i][jj][r] + bias;
        }
    }
}

extern "C" void kernel_launch(void* const* d_in, const int* in_sizes, int n_in,
                              void* d_out, int out_size, void* d_ws, size_t ws_size,
                              hipStream_t stream) {
    const float* img   = (const float*)d_in[0];
    const int*   capix = (const int*)d_in[1];
    const float* W_h0  = (const float*)d_in[2];
    const float* b_h0  = (const float*)d_in[3];
    const float* W_c0  = (const float*)d_in[4];
    const float* b_c0  = (const float*)d_in[5];
    const float* emb   = (const float*)d_in[6];
    const float* W_key = (const float*)d_in[7];
    const float* b_key = (const float*)d_in[8];
    const float* W_ih  = (const float*)d_in[9];
    const float* b_ih  = (const float*)d_in[10];
    const float* W_hh  = (const float*)d_in[11];
    const float* b_hh  = (const float*)d_in[12];
    const float* W_out = (const float*)d_in[13];
    const float* b_out = (const float*)d_in[14];

    float* ws = (float*)d_ws;
    float* gates_buf = ws;                        // 131072 (fm overlaid)
    float* fm        = ws;                        // 32768, dead before first gates write
    float* xbuf      = gates_buf + 131072;        // 81920
    float* cell      = xbuf + 81920;              // 32768
    float* WT        = cell + 32768;              // 2621440
    float* WkT       = WT + 2621440;              // 262144
    unsigned short* outs  = (unsigned short*)(WkT + 262144);   // B*T*ODIM bf16 = 1638400 shorts
    unsigned short* keys2 = outs + (size_t)B * T * ODIM;       // B*HW*U bf16 = 6422528 shorts

    float* logits = (float*)d_out;
    float* attn   = logits + (size_t)B * T * V;

    k_mean<<<(B * C) / 4, 256, 0, stream>>>(img, fm);
    k_init<<<(2 * B * U) / 4, 256, 0, stream>>>(fm, W_h0, b_h0, W_c0, b_c0, xbuf, cell);
    k_wkt<<<dim3(8, 8), 256, 0, stream>>>(W_key, WkT);
    k_keys<<<B * 16, 256, 0, stream>>>(img, WkT, b_key, keys2);
    k_wt<<<dim3(32, 20), 256, 0, stream>>>(W_ih, W_hh, WT);
    k_emb<<<B * T, 256, 0, stream>>>(capix, emb, outs);

    for (int t = 0; t < T; t++) {
        k_step<<<B, 256, 0, stream>>>(outs, xbuf, cell, gates_buf, keys2, img,
                                      b_ih, b_hh, attn, t);
        k_gates4<<<256, 256, 0, stream>>>(xbuf, WT, gates_buf);
    }
    k_step<<<B, 256, 0, stream>>>(outs, xbuf, cell, gates_buf, keys2, img,
                                  b_ih, b_hh, attn, T);

    k_logits3<<<dim3((V + 255) / 256, (B * T) / 256), 256, 0, stream>>>(outs, W_out, b_out, logits);
}

// Round 6
// 1375.052 us; speedup vs baseline: 2.8080x; 1.8856x over previous
//
#include <hip/hip_runtime.h>
#include <math.h>

#define B 64
#define T 20
#define C 512
#define HW 196
#define V 10000
#define E 256
#define U 512
#define G4U 2048
#define ODIM 1280
#define KTOT 1280

typedef short bf8_t __attribute__((ext_vector_type(8)));
typedef float f4_t  __attribute__((ext_vector_type(4)));

__device__ __forceinline__ unsigned short f2bf(float f) {
    unsigned int u = __float_as_uint(f);
    return (unsigned short)((u + 0x7fffu + ((u >> 16) & 1u)) >> 16);
}
__device__ __forceinline__ float bf2f(unsigned short s) {
    return __uint_as_float((unsigned int)s << 16);
}
__device__ __forceinline__ float bflo(unsigned int kv) { return __uint_as_float(kv << 16); }
__device__ __forceinline__ float bfhi(unsigned int kv) { return __uint_as_float(kv & 0xffff0000u); }

// ---------- feats_mean ----------
__global__ void k_mean(const float* __restrict__ img, float* __restrict__ fm) {
    int wave = threadIdx.x >> 6;
    int lane = threadIdx.x & 63;
    int row = blockIdx.x * 4 + wave;
    const float* p = img + (size_t)row * HW;
    float s = p[lane] + p[lane + 64] + p[lane + 128];
    if (lane < 4) s += p[lane + 192];
    for (int off = 32; off > 0; off >>= 1) s += __shfl_down(s, off, 64);
    if (lane == 0) fm[row] = s * (1.0f / HW);
}

// ---------- hid0 -> xb (bf16) hid slot, cell0 ----------
__global__ void k_init(const float* __restrict__ fm,
                       const float* __restrict__ W_h0, const float* __restrict__ b_h0,
                       const float* __restrict__ W_c0, const float* __restrict__ b_c0,
                       unsigned short* __restrict__ xb, float* __restrict__ cell) {
    int wv = blockIdx.x * 4 + (threadIdx.x >> 6);
    int lane = threadIdx.x & 63;
    int which = wv >> 15;
    int r = wv & 32767;
    int b = r >> 9, u = r & 511;
    const float* W = which ? W_c0 : W_h0;
    const float* bias = which ? b_c0 : b_h0;
    const float* f = fm + b * C;
    const float* w = W + (size_t)u * C;
    float s = 0.f;
    #pragma unroll
    for (int c = 0; c < C; c += 64) s += f[c + lane] * w[c + lane];
    for (int off = 32; off > 0; off >>= 1) s += __shfl_down(s, off, 64);
    if (lane == 0) {
        float v = s + bias[u];
        if (which) cell[r] = v;
        else       xb[(size_t)b * KTOT + 768 + u] = f2bf(v);
    }
}

// ---------- W_keyT[c][u] ----------
__global__ void k_wkt(const float* __restrict__ Wk, float* __restrict__ WkT) {
    __shared__ float tile[64][65];
    int u0 = blockIdx.x * 64, c0 = blockIdx.y * 64;
    int x = threadIdx.x & 63, y0 = threadIdx.x >> 6;
    #pragma unroll
    for (int i = 0; i < 16; i++) {
        int r = y0 * 16 + i;
        tile[r][x] = Wk[(size_t)(u0 + r) * C + c0 + x];
    }
    __syncthreads();
    #pragma unroll
    for (int i = 0; i < 16; i++) {
        int r = y0 * 16 + i;
        WkT[(size_t)(c0 + r) * U + u0 + x] = tile[x][r];
    }
}

// ---------- keys2[b][k][u] bf16 ----------
__global__ __launch_bounds__(256) void k_keys(const float* __restrict__ img,
        const float* __restrict__ WkT, const float* __restrict__ b_key,
        unsigned short* __restrict__ keys2) {
    __shared__ unsigned short st[32][200];
    int b = blockIdx.x >> 4;
    int u0 = (blockIdx.x & 15) * 32;
    int wave = __builtin_amdgcn_readfirstlane(threadIdx.x >> 6);
    int lane = threadIdx.x & 63;
    int lk = lane < 49 ? lane : 48;
    const f4_t* imgb = (const f4_t*)(img + (size_t)b * C * HW);
    f4_t acc[8];
    #pragma unroll
    for (int j = 0; j < 8; j++) acc[j] = (f4_t){0.f, 0.f, 0.f, 0.f};
    const float* wp = WkT + u0 + wave * 8;
    for (int c = 0; c < C; c++) {
        f4_t v = imgb[c * 49 + lk];
        const float* w = wp + (size_t)c * U;
        #pragma unroll
        for (int j = 0; j < 8; j++) acc[j] += v * w[j];
    }
    if (lane < 49) {
        #pragma unroll
        for (int j = 0; j < 8; j++) {
            float bk = b_key[u0 + wave * 8 + j];
            int ul = wave * 8 + j;
            int k = lane * 4;
            st[ul][k + 0] = f2bf(acc[j].x + bk);
            st[ul][k + 1] = f2bf(acc[j].y + bk);
            st[ul][k + 2] = f2bf(acc[j].z + bk);
            st[ul][k + 3] = f2bf(acc[j].w + bk);
        }
    }
    __syncthreads();
    int ui = threadIdx.x & 15;
    int kr = threadIdx.x >> 4;
    #pragma unroll
    for (int pass = 0; pass < 13; pass++) {
        int k = pass * 16 + kr;
        if (k < HW) {
            unsigned int lo = st[ui * 2][k];
            unsigned int hi = st[ui * 2 + 1][k];
            *(unsigned int*)&keys2[((size_t)b * HW + k) * U + u0 + ui * 2] = (hi << 16) | lo;
        }
    }
}

// ---------- Wg[j][0:1280] = bf16{ W_ih[j][:], W_hh[j][:] } ----------
__global__ void k_wg(const float* __restrict__ W_ih, const float* __restrict__ W_hh,
                     unsigned short* __restrict__ Wg) {
    int j = blockIdx.x;
    int tid = threadIdx.x;
    const float* s1 = W_ih + (size_t)j * 768;
    const float* s2 = W_hh + (size_t)j * 512;
    unsigned short* dst = Wg + (size_t)j * KTOT;
    #pragma unroll
    for (int p = 0; p < 3; p++) dst[tid + p * 256] = f2bf(s1[tid + p * 256]);
    #pragma unroll
    for (int p = 0; p < 2; p++) dst[768 + tid + p * 256] = f2bf(s2[tid + p * 256]);
}

// ---------- embedding gather + renorm -> outs (bf16) emb slot ----------
__global__ void k_emb(const int* __restrict__ ix, const float* __restrict__ emb,
                      unsigned short* __restrict__ outs) {
    int bt = blockIdx.x;
    int e = threadIdx.x;
    int row = ix[bt];
    float v = emb[(size_t)row * E + e];
    __shared__ float red[4];
    float sq = v * v;
    for (int off = 32; off > 0; off >>= 1) sq += __shfl_down(sq, off, 64);
    int wave = e >> 6, lane = e & 63;
    if (lane == 0) red[wave] = sq;
    __syncthreads();
    float norm = sqrtf(red[0] + red[1] + red[2] + red[3]);
    float scale = fminf(1.0f, 5.0f / fmaxf(norm, 1e-12f));
    outs[(size_t)bt * ODIM + (U + C) + e] = f2bf(v * scale);
}

// ---------- A-kernel: pointwise LSTM + attention; one block per b ----------
__global__ __launch_bounds__(256) void k_step(
    unsigned short* __restrict__ outs, unsigned short* __restrict__ xb,
    float* __restrict__ cell, const float* __restrict__ gates_buf,
    const unsigned short* __restrict__ keys2, const float* __restrict__ img,
    const float* __restrict__ b_ih, const float* __restrict__ b_hh,
    float* __restrict__ attn, int t) {
    int b = blockIdx.x;
    int tid = threadIdx.x;
    int wave = tid >> 6, lane = tid & 63;
    __shared__ float hidS[U];
    __shared__ float wS[256];
    __shared__ float red[4];

    if (t > 0) {
        #pragma unroll
        for (int p = 0; p < 2; p++) {
            int u = tid + p * 256;
            float g[4];
            #pragma unroll
            for (int q = 0; q < 4; q++) {
                int j = q * 512 + u;
                g[q] = gates_buf[(size_t)b * G4U + j] + b_ih[j] + b_hh[j];
            }
            float si = 1.f / (1.f + expf(-g[0]));
            float sf = 1.f / (1.f + expf(-g[1]));
            float tg = tanhf(g[2]);
            float so = 1.f / (1.f + expf(-g[3]));
            int ci = b * U + u;
            float cn = sf * cell[ci] + si * tg;
            float hn = so * tanhf(cn);
            cell[ci] = cn;
            hidS[u] = hn;
            outs[((size_t)b * T + (t - 1)) * ODIM + u] = f2bf(hn);
            xb[(size_t)b * KTOT + 768 + u] = f2bf(hn);
        }
    } else {
        #pragma unroll
        for (int p = 0; p < 2; p++) {
            int u = tid + p * 256;
            hidS[u] = bf2f(xb[(size_t)b * KTOT + 768 + u]);
        }
    }
    if (t >= T) return;
    __syncthreads();

    // scores: thread-per-k, hid broadcast from LDS
    float sc = 0.f;
    if (tid < HW) {
        const uint4* kr = (const uint4*)(keys2 + ((size_t)b * HW + tid) * U);
        float acc = 0.f;
        #pragma unroll 8
        for (int i = 0; i < 64; i++) {
            uint4 kv = kr[i];
            float4 h0 = *(const float4*)&hidS[i * 8];
            float4 h1 = *(const float4*)&hidS[i * 8 + 4];
            acc += bflo(kv.x) * h0.x + bfhi(kv.x) * h0.y
                 + bflo(kv.y) * h0.z + bfhi(kv.y) * h0.w
                 + bflo(kv.z) * h1.x + bfhi(kv.z) * h1.y
                 + bflo(kv.w) * h1.z + bfhi(kv.w) * h1.w;
        }
        sc = acc * 0.044194173824159216f;
    }
    // softmax over 196
    {
        float v = (tid < HW) ? sc : -1e30f;
        float m = v;
        for (int off = 32; off > 0; off >>= 1) m = fmaxf(m, __shfl_down(m, off, 64));
        if (lane == 0) red[wave] = m;
        __syncthreads();
        m = fmaxf(fmaxf(red[0], red[1]), fmaxf(red[2], red[3]));
        float ex = (tid < HW) ? expf(v - m) : 0.f;
        float ssum = ex;
        for (int off = 32; off > 0; off >>= 1) ssum += __shfl_down(ssum, off, 64);
        __syncthreads();
        if (lane == 0) red[wave] = ssum;
        __syncthreads();
        ssum = red[0] + red[1] + red[2] + red[3];
        float w = ex / ssum;
        wS[tid] = w;
        if (tid < HW) attn[((size_t)b * T + t) * HW + tid] = w;
    }
    __syncthreads();

    // context: thread-per-c full dot over k
    {
        const float4* imgb = (const float4*)(img + (size_t)b * C * HW);
        #pragma unroll
        for (int p = 0; p < 2; p++) {
            int c = tid + p * 256;
            const float4* r = imgb + c * 49;
            float acc = 0.f;
            for (int k4 = 0; k4 < 49; k4++) {
                float4 vv = r[k4];
                acc += wS[4 * k4] * vv.x + wS[4 * k4 + 1] * vv.y
                     + wS[4 * k4 + 2] * vv.z + wS[4 * k4 + 3] * vv.w;
            }
            xb[(size_t)b * KTOT + 256 + c] = f2bf(acc);
            outs[((size_t)b * T + t) * ODIM + U + c] = f2bf(acc);
        }
    }
    // emb (bf16) -> xb via uint copy
    if (tid < 128) {
        const unsigned int* src = (const unsigned int*)(outs + ((size_t)b * T + t) * ODIM);
        unsigned int* dst = (unsigned int*)(xb + (size_t)b * KTOT);
        dst[tid] = src[512 + tid];
    }
}

// ---------- gates: bf16 MFMA GEMM  gates[b][j] = sum_k xb[b][k]*Wg[j][k] ----------
// 32 blocks: j0 = blk*64. Wave w: n-tile w*16, m 0..63 (4 tiles). K chunks of 64.
__global__ __launch_bounds__(256) void k_gates5(
    const unsigned short* __restrict__ xb, const unsigned short* __restrict__ Wg,
    float* __restrict__ gates_buf) {
    __shared__ unsigned short As[64][72];
    __shared__ unsigned short Bs[64][72];
    int j0 = blockIdx.x * 64;
    int tid = threadIdx.x;
    int lane = tid & 63;
    int wv = __builtin_amdgcn_readfirstlane(tid >> 6);
    int m16 = lane & 15, quad = lane >> 4;
    int r = tid >> 2;          // 0..63 staging row
    int kq = tid & 3;          // 16-ushort group

    f4_t acc[4];
    #pragma unroll
    for (int i = 0; i < 4; i++) acc[i] = (f4_t){0.f, 0.f, 0.f, 0.f};

    for (int k0 = 0; k0 < KTOT; k0 += 64) {
        const uint4* ap = (const uint4*)&xb[(size_t)r * KTOT + k0 + kq * 16];
        uint4 a0 = ap[0], a1 = ap[1];
        const uint4* bp = (const uint4*)&Wg[(size_t)(j0 + r) * KTOT + k0 + kq * 16];
        uint4 b0 = bp[0], b1 = bp[1];
        *(uint4*)&As[r][kq * 16] = a0;
        *(uint4*)&As[r][kq * 16 + 8] = a1;
        *(uint4*)&Bs[r][kq * 16] = b0;
        *(uint4*)&Bs[r][kq * 16 + 8] = b1;
        __syncthreads();
        #pragma unroll
        for (int h = 0; h < 2; h++) {
            bf8_t bfr = *(const bf8_t*)&Bs[wv * 16 + m16][h * 32 + quad * 8];
            #pragma unroll
            for (int i = 0; i < 4; i++) {
                bf8_t afr = *(const bf8_t*)&As[i * 16 + m16][h * 32 + quad * 8];
                acc[i] = __builtin_amdgcn_mfma_f32_16x16x32_bf16(afr, bfr, acc[i], 0, 0, 0);
            }
        }
        __syncthreads();
    }
    int n = j0 + wv * 16 + m16;
    #pragma unroll
    for (int i = 0; i < 4; i++) {
        int mb = i * 16 + quad * 4;
        #pragma unroll
        for (int rr = 0; rr < 4; rr++)
            gates_buf[(size_t)(mb + rr) * G4U + n] = acc[i][rr];
    }
}

// ---------- logits: bf16 MFMA, 128x128 tile, 64x64 per wave ----------
__global__ __launch_bounds__(256) void k_logits4(
    const unsigned short* __restrict__ A, const float* __restrict__ Wo,
    const float* __restrict__ bo, float* __restrict__ Cout) {
    __shared__ unsigned short As[128][72];
    __shared__ unsigned short Bs[128][72];
    int n0 = blockIdx.x * 128;
    int m0 = blockIdx.y * 128;
    int tid = threadIdx.x;
    int lane = tid & 63, wv = tid >> 6;
    int mw = (wv >> 1) * 64, nw = (wv & 1) * 64;
    int m16 = lane & 15, quad = lane >> 4;
    int srow = tid >> 1, shalf = tid & 1;

    f4_t acc[4][4];
    #pragma unroll
    for (int i = 0; i < 4; i++)
        #pragma unroll
        for (int j = 0; j < 4; j++)
            acc[i][j] = (f4_t){0.f, 0.f, 0.f, 0.f};

    for (int k0 = 0; k0 < KTOT; k0 += 64) {
        {
            const uint4* ap = (const uint4*)&A[(size_t)(m0 + srow) * KTOT + k0 + shalf * 32];
            uint4 a0 = ap[0], a1 = ap[1], a2 = ap[2], a3 = ap[3];
            uint4* dst = (uint4*)&As[srow][shalf * 32];
            dst[0] = a0; dst[1] = a1; dst[2] = a2; dst[3] = a3;
        }
        {
            int n = n0 + srow;
            uint4 q[4];
            if (n < V) {
                const float4* bp = (const float4*)&Wo[(size_t)n * KTOT + k0 + shalf * 32];
                #pragma unroll
                for (int g = 0; g < 4; g++) {
                    float4 f0 = bp[g * 2], f1 = bp[g * 2 + 1];
                    q[g].x = ((unsigned int)f2bf(f0.y) << 16) | f2bf(f0.x);
                    q[g].y = ((unsigned int)f2bf(f0.w) << 16) | f2bf(f0.z);
                    q[g].z = ((unsigned int)f2bf(f1.y) << 16) | f2bf(f1.x);
                    q[g].w = ((unsigned int)f2bf(f1.w) << 16) | f2bf(f1.z);
                }
            } else {
                #pragma unroll
                for (int g = 0; g < 4; g++) q[g] = (uint4){0u, 0u, 0u, 0u};
            }
            uint4* dst = (uint4*)&Bs[srow][shalf * 32];
            #pragma unroll
            for (int g = 0; g < 4; g++) dst[g] = q[g];
        }
        __syncthreads();
        #pragma unroll
        for (int h = 0; h < 2; h++) {
            bf8_t af[4], bf[4];
            #pragma unroll
            for (int i = 0; i < 4; i++)
                af[i] = *(const bf8_t*)&As[mw + i * 16 + m16][h * 32 + quad * 8];
            #pragma unroll
            for (int j = 0; j < 4; j++)
                bf[j] = *(const bf8_t*)&Bs[nw + j * 16 + m16][h * 32 + quad * 8];
            #pragma unroll
            for (int i = 0; i < 4; i++)
                #pragma unroll
                for (int j = 0; j < 4; j++)
                    acc[i][j] = __builtin_amdgcn_mfma_f32_16x16x32_bf16(af[i], bf[j], acc[i][j], 0, 0, 0);
        }
        __syncthreads();
    }

    #pragma unroll
    for (int j = 0; j < 4; j++) {
        int n = n0 + nw + j * 16 + m16;
        if (n >= V) continue;
        float bias = bo[n];
        #pragma unroll
        for (int i = 0; i < 4; i++) {
            int mb = m0 + mw + i * 16 + quad * 4;
            #pragma unroll
            for (int r = 0; r < 4; r++)
                Cout[(size_t)(mb + r) * V + n] = acc[i][j][r] + bias;
        }
    }
}

extern "C" void kernel_launch(void* const* d_in, const int* in_sizes, int n_in,
                              void* d_out, int out_size, void* d_ws, size_t ws_size,
                              hipStream_t stream) {
    const float* img   = (const float*)d_in[0];
    const int*   capix = (const int*)d_in[1];
    const float* W_h0  = (const float*)d_in[2];
    const float* b_h0  = (const float*)d_in[3];
    const float* W_c0  = (const float*)d_in[4];
    const float* b_c0  = (const float*)d_in[5];
    const float* emb   = (const float*)d_in[6];
    const float* W_key = (const float*)d_in[7];
    const float* b_key = (const float*)d_in[8];
    const float* W_ih  = (const float*)d_in[9];
    const float* b_ih  = (const float*)d_in[10];
    const float* W_hh  = (const float*)d_in[11];
    const float* b_hh  = (const float*)d_in[12];
    const float* W_out = (const float*)d_in[13];
    const float* b_out = (const float*)d_in[14];

    float* ws = (float*)d_ws;
    float* gates_buf = ws;                        // 131072 f (fm overlaid)
    float* fm        = ws;                        // 32768 f, dead before t=0 gates
    float* cell      = gates_buf + 131072;        // 32768 f
    float* WkT       = cell + 32768;              // 262144 f
    unsigned short* Wg    = (unsigned short*)(WkT + 262144);  // 2621440 ush
    unsigned short* xb    = Wg + 2621440;                      // 81920 ush
    unsigned short* outs  = xb + 81920;                        // 1638400 ush
    unsigned short* keys2 = outs + (size_t)B * T * ODIM;       // 6422528 ush

    float* logits = (float*)d_out;
    float* attn   = logits + (size_t)B * T * V;

    k_mean<<<(B * C) / 4, 256, 0, stream>>>(img, fm);
    k_init<<<(2 * B * U) / 4, 256, 0, stream>>>(fm, W_h0, b_h0, W_c0, b_c0, xb, cell);
    k_wkt<<<dim3(8, 8), 256, 0, stream>>>(W_key, WkT);
    k_keys<<<B * 16, 256, 0, stream>>>(img, WkT, b_key, keys2);
    k_wg<<<G4U, 256, 0, stream>>>(W_ih, W_hh, Wg);
    k_emb<<<B * T, 256, 0, stream>>>(capix, emb, outs);

    for (int t = 0; t < T; t++) {
        k_step<<<B, 256, 0, stream>>>(outs, xb, cell, gates_buf, keys2, img,
                                      b_ih, b_hh, attn, t);
        k_gates5<<<32, 256, 0, stream>>>(xb, Wg, gates_buf);
    }
    k_step<<<B, 256, 0, stream>>>(outs, xb, cell, gates_buf, keys2, img,
                                  b_ih, b_hh, attn, T);

    k_logits4<<<dim3((V + 127) / 128, (B * T) / 128), 256, 0, stream>>>(outs, W_out, b_out, logits);
}